// Round 10
// baseline (124.742 us; speedup 1.0000x reference)
//
#include <hip/hip_runtime.h>
#include <hip/hip_bf16.h>

typedef __bf16 bf16x8 __attribute__((ext_vector_type(8)));
typedef __bf16 bf16x4 __attribute__((ext_vector_type(4)));
typedef float  f32x4  __attribute__((ext_vector_type(4)));

#define NB 64
#define LL 1024
#define DD 64
#define HK 512        // keys per LDS half
#define PAN 264       // bf16 stride of panel rows (528 B)

#define PANEL_LDS (HK * DD * 2 + 8 * 16 * PAN * 2)   // 64K + 66K = 133120 B

#define WS_VT_OFF 0
#define WS_KB_OFF ((size_t)8 * 1024 * 1024)
#define WS_NEED   ((size_t)16 * 1024 * 1024)

#if __has_builtin(__builtin_amdgcn_exp2f)
#define EXP2(x) __builtin_amdgcn_exp2f(x)
#else
#define EXP2(x) exp2f(x)
#endif

// ---------- prep: V -> Vt bf16 [b][d][key]  +  K -> bf16 [b][key][d] --------
__global__ __launch_bounds__(256)
void preconvert_kv(const float* __restrict__ k, const float* __restrict__ v,
                   __bf16* __restrict__ kbf, __bf16* __restrict__ vt) {
  const int blk = blockIdx.x, tid = threadIdx.x;
  if (blk < NB * (LL / 64)) {
    const int b = blk >> 4, t = blk & 15;
    __shared__ float tile[64][65];
    const float* src = v + ((size_t)b * LL + t * 64) * DD;
    for (int i = tid; i < 64 * 16; i += 256) {
      const int row = i >> 4, c4 = (i & 15) * 4;
      f32x4 x = *(const f32x4*)(src + row * DD + c4);
      tile[row][c4 + 0] = x[0]; tile[row][c4 + 1] = x[1];
      tile[row][c4 + 2] = x[2]; tile[row][c4 + 3] = x[3];
    }
    __syncthreads();
    __bf16* dst = vt + (size_t)b * DD * LL + t * 64;
    for (int i = tid; i < 64 * 8; i += 256) {
      const int d = i >> 3, k8 = (i & 7) * 8;
      bf16x8 o;
      #pragma unroll
      for (int j = 0; j < 8; ++j) o[j] = (__bf16)tile[k8 + j][d];
      *(bf16x8*)(dst + (size_t)d * LL + k8) = o;
    }
  } else {
    const size_t base = ((size_t)(blk - 1024) * 256 + tid) * 8;
    const f32x4* s = (const f32x4*)(k + base);
    f32x4 x0 = s[0], x1 = s[1];
    bf16x8 o;
    #pragma unroll
    for (int j = 0; j < 4; ++j) { o[j] = (__bf16)x0[j]; o[4 + j] = (__bf16)x1[j]; }
    *(bf16x8*)(kbf + base) = o;
  }
}

// ---------- main: fused 2-pass, panel-buffered 1KB-burst attn stores --------
__global__ __launch_bounds__(512, 1)
void sdpa_panel(const float* __restrict__ q, const __bf16* __restrict__ kbf,
                const __bf16* __restrict__ vt, const float* __restrict__ scale_p,
                float* __restrict__ out) {
  extern __shared__ char smem[];
  __bf16* Klds = (__bf16*)smem;                    // [512][64], XOR-swizzled
  __bf16* Pan  = (__bf16*)(smem + HK * DD * 2);    // [8 waves][16][PAN]

  const int tid  = threadIdx.x;
  const int lane = tid & 63;
  const int w    = tid >> 6;
  const int l15  = lane & 15;
  const int lg   = lane >> 4;

  int bid = blockIdx.x;                    // 256 blocks
  bid = (bid & 7) * 32 + (bid >> 3);       // XCD-chunked, bijective
  const int b     = bid >> 2;
  const int qrow0 = (bid & 3) * 256 + w * 32;

  const float scale2 = scale_p[0] * 1.4426950408889634f;
  const __bf16* kb = kbf + (size_t)b * LL * DD;
  const __bf16* vb = vt  + (size_t)b * DD * LL;
  float* ctxb  = out + ((size_t)b * LL + qrow0) * DD;
  float* attnb = out + (size_t)NB * LL * DD + (size_t)b * LL * LL
               + (size_t)qrow0 * LL;

  // ---- Q fragments, 2 subtiles of 16 rows (scale2 folded) ----
  bf16x8 aq[2][2];
  #pragma unroll
  for (int u = 0; u < 2; ++u) {
    const float* qrow = q + ((size_t)b * LL + qrow0 + u * 16 + l15) * DD;
    #pragma unroll
    for (int s = 0; s < 2; ++s) {
      const f32x4* p4 = (const f32x4*)(qrow + s * 32 + lg * 8);
      f32x4 x0 = p4[0], x1 = p4[1];
      #pragma unroll
      for (int j = 0; j < 4; ++j) {
        aq[u][s][j]     = (__bf16)(x0[j] * scale2);
        aq[u][s][4 + j] = (__bf16)(x1[j] * scale2);
      }
    }
  }

  const int xsw = (l15 & 7) * 8;
  __bf16* pw = Pan + (size_t)w * 16 * PAN;     // wave-private panel

  // ================= pass 1: denominators (2 halves) =======================
  float ls[2] = {0.f, 0.f};
  for (int h = 0; h < 2; ++h) {
    __syncthreads();
    #pragma unroll
    for (int it = 0; it < 8; ++it) {           // stage 512 keys from bf16 K
      const int c = it * 512 + tid;            // 4096 chunks of 8 bf16
      const int row = c >> 3, slot = c & 7;
      bf16x8 t = *(const bf16x8*)(kb + (size_t)(h * HK + row) * 64 + slot * 8);
      *(bf16x8*)(Klds + row * 64 + ((slot * 8) ^ ((row & 7) * 8))) = t;
    }
    __syncthreads();
    for (int kt = 0; kt < HK / 32; ++kt) {
      bf16x8 bk[2][2];
      #pragma unroll
      for (int f = 0; f < 2; ++f)
        #pragma unroll
        for (int s = 0; s < 2; ++s)
          bk[f][s] = *(const bf16x8*)(Klds + (kt * 32 + f * 16 + l15) * 64
                                           + ((s * 32 + lg * 8) ^ xsw));
      #pragma unroll
      for (int u = 0; u < 2; ++u) {
        f32x4 sacc[2] = {{0.f,0.f,0.f,0.f},{0.f,0.f,0.f,0.f}};
        #pragma unroll
        for (int s = 0; s < 2; ++s)
          #pragma unroll
          for (int f = 0; f < 2; ++f)
            sacc[f] = __builtin_amdgcn_mfma_f32_16x16x32_bf16(bk[f][s], aq[u][s], sacc[f], 0, 0, 0);
        #pragma unroll
        for (int f = 0; f < 2; ++f)
          #pragma unroll
          for (int r = 0; r < 4; ++r)
            ls[u] += EXP2(sacc[f][r]);
      }
    }
  }
  #pragma unroll
  for (int u = 0; u < 2; ++u) {
    ls[u] += __shfl_xor(ls[u], 16, 64);
    ls[u] += __shfl_xor(ls[u], 32, 64);
  }
  const float rl[2] = {1.0f / ls[0], 1.0f / ls[1]};

  // ================= pass 2: panels of 16 rows x 256 keys ==================
  f32x4 cacc[2][4];
  #pragma unroll
  for (int u = 0; u < 2; ++u)
    #pragma unroll
    for (int g = 0; g < 4; ++g)
      cacc[u][g] = (f32x4){0.f, 0.f, 0.f, 0.f};

  for (int h = 0; h < 2; ++h) {
    __syncthreads();
    #pragma unroll
    for (int it = 0; it < 8; ++it) {
      const int c = it * 512 + tid;
      const int row = c >> 3, slot = c & 7;
      bf16x8 t = *(const bf16x8*)(kb + (size_t)(h * HK + row) * 64 + slot * 8);
      *(bf16x8*)(Klds + row * 64 + ((slot * 8) ^ ((row & 7) * 8))) = t;
    }
    __syncthreads();

    for (int pc = 0; pc < 2; ++pc) {
      #pragma unroll
      for (int u = 0; u < 2; ++u) {
        // ---- compute 16 rows x 256 keys into the wave panel ----
        for (int kt8 = 0; kt8 < 8; ++kt8) {
          const int kt = pc * 8 + kt8;

          bf16x8 bv[4];
          #pragma unroll
          for (int g = 0; g < 4; ++g)
            bv[g] = *(const bf16x8*)(vb + (size_t)(g * 16 + l15) * LL
                                        + h * HK + kt * 32 + lg * 8);

          bf16x8 bk[2][2];
          #pragma unroll
          for (int f = 0; f < 2; ++f)
            #pragma unroll
            for (int s = 0; s < 2; ++s)
              bk[f][s] = *(const bf16x8*)(Klds + (kt * 32 + f * 16 + l15) * 64
                                               + ((s * 32 + lg * 8) ^ xsw));

          f32x4 sacc[2] = {{0.f,0.f,0.f,0.f},{0.f,0.f,0.f,0.f}};
          #pragma unroll
          for (int s = 0; s < 2; ++s)
            #pragma unroll
            for (int f = 0; f < 2; ++f)
              sacc[f] = __builtin_amdgcn_mfma_f32_16x16x32_bf16(bk[f][s], aq[u][s], sacc[f], 0, 0, 0);

          // p -> bf16 into panel (lane owns q=l15; k = kt8*32 + f*16 + lg*4 + r)
          #pragma unroll
          for (int f = 0; f < 2; ++f) {
            bf16x4 pb;
            #pragma unroll
            for (int r = 0; r < 4; ++r)
              pb[r] = (__bf16)(EXP2(sacc[f][r]) * rl[u]);
            *(bf16x4*)(pw + l15 * PAN + kt8 * 32 + f * 16 + lg * 4) = pb;
          }

          // PV A-operand straight from the panel
          bf16x8 pa = *(const bf16x8*)(pw + l15 * PAN + kt8 * 32 + lg * 8);
          #pragma unroll
          for (int g = 0; g < 4; ++g)
            cacc[u][g] = __builtin_amdgcn_mfma_f32_16x16x32_bf16(pa, bv[g], cacc[u][g], 0, 0, 0);
        }

        // ---- store panel: 16 rows, each a single 1 KB contiguous burst ----
        float* ab = attnb + (size_t)(u * 16) * LL + h * HK + pc * 256;
        #pragma unroll
        for (int r = 0; r < 16; ++r) {
          const uint2 rw = *(const uint2*)(pw + r * PAN + lane * 4);
          f32x4 o;
          o[0] = __uint_as_float(rw.x << 16);
          o[1] = __uint_as_float(rw.x & 0xffff0000u);
          o[2] = __uint_as_float(rw.y << 16);
          o[3] = __uint_as_float(rw.y & 0xffff0000u);
          *(f32x4*)(ab + (size_t)r * LL + lane * 4) = o;
        }
      }
    }
  }

  // ---- context epilogue ----
  #pragma unroll
  for (int u = 0; u < 2; ++u)
    #pragma unroll
    for (int g = 0; g < 4; ++g)
      #pragma unroll
      for (int r = 0; r < 4; ++r)
        ctxb[(size_t)(u * 16 + lg * 4 + r) * DD + g * 16 + l15] = cacc[u][g][r];
}

// ====================== fallback (R1 kernel, proven) ========================
#define BQ 64
#define BK 32
#define KSTRIDE 72
#define VSTRIDE 40
#define PSTRIDE 48

__global__ __launch_bounds__(256, 4)
void sdpa_fallback(const float* __restrict__ q, const float* __restrict__ k,
                   const float* __restrict__ v, const float* __restrict__ scale_p,
                   float* __restrict__ out) {
  const int tid  = threadIdx.x;
  const int lane = tid & 63;
  const int w    = tid >> 6;
  int bid = blockIdx.x;
  bid = (bid & 7) * 128 + (bid >> 3);
  const int b    = bid >> 4;
  const int qblk = (bid & 15) * BQ;

  __shared__ __bf16 Ks[BK * KSTRIDE];
  __shared__ __bf16 Vs[DD * VSTRIDE];
  __shared__ __bf16 Pp[4][16 * PSTRIDE];

  const float scale = scale_p[0];
  const float* qb = q + ((size_t)b * LL + qblk) * DD;
  const float* kb = k + (size_t)b * LL * DD;
  const float* vb = v + (size_t)b * LL * DD;
  float* ctx  = out + ((size_t)b * LL + qblk) * DD;
  float* attn = out + (size_t)NB * LL * DD + (size_t)b * LL * LL + (size_t)qblk * LL;

  const int l15 = lane & 15;
  const int lg  = lane >> 4;
  const int dchunk = lg * 8;

  bf16x8 aq[2];
  {
    const float* qrow = qb + (size_t)(w * 16 + l15) * DD;
    #pragma unroll
    for (int s = 0; s < 2; ++s) {
      const f32x4* p4 = (const f32x4*)(qrow + s * 32 + dchunk);
      f32x4 x0 = p4[0], x1 = p4[1];
      #pragma unroll
      for (int j = 0; j < 4; ++j) {
        aq[s][j]     = (__bf16)(x0[j] * scale);
        aq[s][4 + j] = (__bf16)(x1[j] * scale);
      }
    }
  }

  const int srow = tid >> 3;
  const int sd0  = (tid & 7) * 8;

  float lpart[4] = {0.f, 0.f, 0.f, 0.f};
  for (int kt = 0; kt < LL / BK; ++kt) {
    __syncthreads();
    {
      const f32x4* src = (const f32x4*)(kb + (size_t)(kt * BK + srow) * DD + sd0);
      f32x4 x0 = src[0], x1 = src[1];
      bf16x8 t;
      #pragma unroll
      for (int j = 0; j < 4; ++j) { t[j] = (__bf16)x0[j]; t[4 + j] = (__bf16)x1[j]; }
      *(bf16x8*)&Ks[srow * KSTRIDE + sd0] = t;
    }
    __syncthreads();
    f32x4 sacc[2] = {{0.f,0.f,0.f,0.f},{0.f,0.f,0.f,0.f}};
    #pragma unroll
    for (int s = 0; s < 2; ++s)
      #pragma unroll
      for (int f = 0; f < 2; ++f) {
        bf16x8 bk = *(const bf16x8*)&Ks[(f * 16 + l15) * KSTRIDE + s * 32 + dchunk];
        sacc[f] = __builtin_amdgcn_mfma_f32_16x16x32_bf16(aq[s], bk, sacc[f], 0, 0, 0);
      }
    #pragma unroll
    for (int f = 0; f < 2; ++f)
      #pragma unroll
      for (int r = 0; r < 4; ++r)
        lpart[r] += __expf(sacc[f][r]);
  }
  #pragma unroll
  for (int m = 1; m < 16; m <<= 1)
    #pragma unroll
    for (int r = 0; r < 4; ++r)
      lpart[r] += __shfl_xor(lpart[r], m, 64);
  float rl[4];
  #pragma unroll
  for (int r = 0; r < 4; ++r) rl[r] = 1.0f / lpart[r];

  f32x4 cacc[4] = {{0.f,0.f,0.f,0.f},{0.f,0.f,0.f,0.f},
                   {0.f,0.f,0.f,0.f},{0.f,0.f,0.f,0.f}};
  for (int kt = 0; kt < LL / BK; ++kt) {
    __syncthreads();
    {
      const f32x4* src = (const f32x4*)(kb + (size_t)(kt * BK + srow) * DD + sd0);
      f32x4 x0 = src[0], x1 = src[1];
      bf16x8 t;
      #pragma unroll
      for (int j = 0; j < 4; ++j) { t[j] = (__bf16)x0[j]; t[4 + j] = (__bf16)x1[j]; }
      *(bf16x8*)&Ks[srow * KSTRIDE + sd0] = t;
      const f32x4* vsrc = (const f32x4*)(vb + (size_t)(kt * BK + srow) * DD + sd0);
      f32x4 y0 = vsrc[0], y1 = vsrc[1];
      #pragma unroll
      for (int j = 0; j < 4; ++j) {
        Vs[(sd0 + j)     * VSTRIDE + srow] = (__bf16)y0[j];
        Vs[(sd0 + 4 + j) * VSTRIDE + srow] = (__bf16)y1[j];
      }
    }
    __syncthreads();
    f32x4 sacc[2] = {{0.f,0.f,0.f,0.f},{0.f,0.f,0.f,0.f}};
    #pragma unroll
    for (int s = 0; s < 2; ++s)
      #pragma unroll
      for (int f = 0; f < 2; ++f) {
        bf16x8 bk = *(const bf16x8*)&Ks[(f * 16 + l15) * KSTRIDE + s * 32 + dchunk];
        sacc[f] = __builtin_amdgcn_mfma_f32_16x16x32_bf16(aq[s], bk, sacc[f], 0, 0, 0);
      }
    #pragma unroll
    for (int f = 0; f < 2; ++f)
      #pragma unroll
      for (int r = 0; r < 4; ++r) {
        const int row = lg * 4 + r;
        float p = __expf(sacc[f][r]) * rl[r];
        attn[(size_t)(w * 16 + row) * LL + (kt * BK + f * 16 + l15)] = p;
        Pp[w][row * PSTRIDE + f * 16 + l15] = (__bf16)p;
      }
    bf16x8 pa = *(const bf16x8*)&Pp[w][l15 * PSTRIDE + lg * 8];
    #pragma unroll
    for (int g = 0; g < 4; ++g) {
      bf16x8 bv = *(const bf16x8*)&Vs[(g * 16 + l15) * VSTRIDE + lg * 8];
      cacc[g] = __builtin_amdgcn_mfma_f32_16x16x32_bf16(pa, bv, cacc[g], 0, 0, 0);
    }
  }
  #pragma unroll
  for (int g = 0; g < 4; ++g)
    #pragma unroll
    for (int r = 0; r < 4; ++r)
      ctx[(size_t)(w * 16 + lg * 4 + r) * DD + g * 16 + l15] = cacc[g][r];
}

extern "C" void kernel_launch(void* const* d_in, const int* in_sizes, int n_in,
                              void* d_out, int out_size, void* d_ws, size_t ws_size,
                              hipStream_t stream) {
  const float* q = (const float*)d_in[0];
  const float* k = (const float*)d_in[1];
  const float* v = (const float*)d_in[2];
  const float* s = (const float*)d_in[3];
  float* out = (float*)d_out;

  if (ws_size >= WS_NEED) {
    __bf16* vt  = (__bf16*)((char*)d_ws + WS_VT_OFF);
    __bf16* kbf = (__bf16*)((char*)d_ws + WS_KB_OFF);
    preconvert_kv<<<dim3(3072), dim3(256), 0, stream>>>(k, v, kbf, vt);
    (void)hipFuncSetAttribute((const void*)sdpa_panel,
                              hipFuncAttributeMaxDynamicSharedMemorySize, PANEL_LDS);
    sdpa_panel<<<dim3(256), dim3(512), PANEL_LDS, stream>>>(q, kbf, vt, s, out);
  } else {
    sdpa_fallback<<<dim3(NB * (LL / 64)), dim3(256), 0, stream>>>(q, k, v, s, out);
  }
}

// Round 11
// 123.465 us; speedup vs baseline: 1.0103x; 1.0103x over previous
//
#include <hip/hip_runtime.h>
#include <hip/hip_bf16.h>

typedef __bf16 bf16x8 __attribute__((ext_vector_type(8)));
typedef __bf16 bf16x4 __attribute__((ext_vector_type(4)));
typedef float  f32x4  __attribute__((ext_vector_type(4)));

#define NB 64
#define LL 1024
#define DD 64
#define PB 40   // bf16 stride for Pw rows (80 B: b128-aligned, low-conflict)

#define LDS_K_BYTES (LL * DD * 2)                       // 128 KiB
#define LDS_TOTAL   (LDS_K_BYTES + 8 * 16 * PB * 2)     // +10 KiB Pw

#if __has_builtin(__builtin_amdgcn_exp2f)
#define EXP2(x) __builtin_amdgcn_exp2f(x)
#else
#define EXP2(x) exp2f(x)
#endif

// ---------------- V pre-pass: transpose+convert V -> Vt bf16 [b][d][key] ----
__global__ __launch_bounds__(256)
void preconvert_v(const float* __restrict__ v, __bf16* __restrict__ vt) {
  const int blk = blockIdx.x, tid = threadIdx.x;
  const int b = blk >> 4, t = blk & 15;   // 64-key tile t of batch b
  __shared__ float tile[64][65];
  const float* src = v + ((size_t)b * LL + t * 64) * DD;
  for (int i = tid; i < 64 * 16; i += 256) {
    const int row = i >> 4, c4 = (i & 15) * 4;
    f32x4 x = *(const f32x4*)(src + row * DD + c4);
    tile[row][c4 + 0] = x[0]; tile[row][c4 + 1] = x[1];
    tile[row][c4 + 2] = x[2]; tile[row][c4 + 3] = x[3];
  }
  __syncthreads();
  __bf16* dst = vt + (size_t)b * DD * LL + t * 64;
  for (int i = tid; i < 64 * 8; i += 256) {
    const int d = i >> 3, k8 = (i & 7) * 8;
    bf16x8 o;
    #pragma unroll
    for (int j = 0; j < 8; ++j) o[j] = (__bf16)tile[k8 + j][d];
    *(bf16x8*)(dst + (size_t)d * LL + k8) = o;
  }
}

// ---------------- fused main: whole-K-in-LDS, phase-interleaved waves -------
__global__ __launch_bounds__(512, 1)
void sdpa_fused(const float* __restrict__ q, const float* __restrict__ kf,
                const __bf16* __restrict__ vt, const float* __restrict__ scale_p,
                float* __restrict__ out) {
  extern __shared__ char smem[];
  __bf16* Klds = (__bf16*)smem;                     // [1024][64], XOR-swizzled
  __bf16* Pw   = (__bf16*)(smem + LDS_K_BYTES);     // [8 waves][16][PB]

  const int tid  = threadIdx.x;
  const int lane = tid & 63;
  const int w    = tid >> 6;
  const int l15  = lane & 15;
  const int lg   = lane >> 4;

  int bid = blockIdx.x;                      // 256 blocks
  bid = (bid & 7) * 32 + (bid >> 3);         // XCD j -> batches [j*8, j*8+8)
  const int b     = bid >> 2;
  const int qrow0 = (bid & 3) * 256 + w * 32;

  // fold log2(e) into the scale: v_exp_f32 computes 2^x natively
  const float scale2 = scale_p[0] * 1.4426950408889634f;
  const float* kb = kf + (size_t)b * LL * DD;       // fp32 K of this batch
  const __bf16* vb = vt + (size_t)b * DD * LL;      // bf16 V^T of this batch
  float* ctxb  = out + ((size_t)b * LL + qrow0) * DD;
  float* attnb = out + (size_t)NB * LL * DD + (size_t)b * LL * LL
               + (size_t)qrow0 * LL;

  // ---- stage ALL of K: fp32 global -> bf16 LDS, swizzled ----
  #pragma unroll
  for (int it = 0; it < 16; ++it) {
    const int c = it * 512 + tid;            // 8192 chunks of 8 elems
    const int row = c >> 3, slot = c & 7;
    const f32x4* s4 = (const f32x4*)(kb + (size_t)c * 8);
    f32x4 x0 = s4[0], x1 = s4[1];
    bf16x8 t;
    #pragma unroll
    for (int j = 0; j < 4; ++j) { t[j] = (__bf16)x0[j]; t[4 + j] = (__bf16)x1[j]; }
    *(bf16x8*)(Klds + row * 64 + ((slot * 8) ^ ((row & 7) * 8))) = t;
  }

  // ---- Q fragments, 2 subtiles of 16 rows (scale2 folded) ----
  bf16x8 aq[2][2];
  #pragma unroll
  for (int u = 0; u < 2; ++u) {
    const float* qrow = q + ((size_t)b * LL + qrow0 + u * 16 + l15) * DD;
    #pragma unroll
    for (int s = 0; s < 2; ++s) {
      const f32x4* p4 = (const f32x4*)(qrow + s * 32 + lg * 8);
      f32x4 x0 = p4[0], x1 = p4[1];
      #pragma unroll
      for (int j = 0; j < 4; ++j) {
        aq[u][s][j]     = (__bf16)(x0[j] * scale2);
        aq[u][s][4 + j] = (__bf16)(x1[j] * scale2);
      }
    }
  }

  __syncthreads();   // K resident — the only barrier

  const int xsw = (l15 & 7) * 8;            // read-side swizzle
  __bf16* prow = Pw + (w * 16 + l15) * PB;  // wave-private P row (q = l15)

  // ================= phase A: pass1(u0) — denominators only ================
  float ls0 = 0.f;
  for (int kt = 0; kt < LL / 32; ++kt) {
    bf16x8 bk[2][2];
    #pragma unroll
    for (int f = 0; f < 2; ++f)
      #pragma unroll
      for (int s = 0; s < 2; ++s)
        bk[f][s] = *(const bf16x8*)(Klds + (kt * 32 + f * 16 + l15) * 64
                                         + ((s * 32 + lg * 8) ^ xsw));
    f32x4 sacc[2] = {{0.f,0.f,0.f,0.f},{0.f,0.f,0.f,0.f}};
    #pragma unroll
    for (int s = 0; s < 2; ++s)
      #pragma unroll
      for (int f = 0; f < 2; ++f)
        sacc[f] = __builtin_amdgcn_mfma_f32_16x16x32_bf16(bk[f][s], aq[0][s], sacc[f], 0, 0, 0);
    #pragma unroll
    for (int f = 0; f < 2; ++f)
      #pragma unroll
      for (int r = 0; r < 4; ++r)
        ls0 += EXP2(sacc[f][r]);
  }
  ls0 += __shfl_xor(ls0, 16, 64);
  ls0 += __shfl_xor(ls0, 32, 64);
  const float rl0 = 1.0f / ls0;

  // ============ phase B: pass2(u0) interleaved with pass1(u1) ==============
  f32x4 cacc0[4], cacc1[4];
  #pragma unroll
  for (int g = 0; g < 4; ++g) {
    cacc0[g] = (f32x4){0.f, 0.f, 0.f, 0.f};
    cacc1[g] = (f32x4){0.f, 0.f, 0.f, 0.f};
  }
  float ls1 = 0.f;

  bf16x8 bvn[4];
  #pragma unroll
  for (int g = 0; g < 4; ++g)
    bvn[g] = *(const bf16x8*)(vb + (size_t)(g * 16 + l15) * LL + lg * 8);

  for (int kt = 0; kt < LL / 32; ++kt) {
    bf16x8 bvc[4];
    #pragma unroll
    for (int g = 0; g < 4; ++g) bvc[g] = bvn[g];
    if (kt + 1 < LL / 32) {
      #pragma unroll
      for (int g = 0; g < 4; ++g)
        bvn[g] = *(const bf16x8*)(vb + (size_t)(g * 16 + l15) * LL
                                     + (kt + 1) * 32 + lg * 8);
    }

    bf16x8 bk[2][2];
    #pragma unroll
    for (int f = 0; f < 2; ++f)
      #pragma unroll
      for (int s = 0; s < 2; ++s)
        bk[f][s] = *(const bf16x8*)(Klds + (kt * 32 + f * 16 + l15) * 64
                                         + ((s * 32 + lg * 8) ^ xsw));

    // QK for BOTH subtiles off the same bk fragments
    f32x4 s0[2] = {{0.f,0.f,0.f,0.f},{0.f,0.f,0.f,0.f}};
    f32x4 s1[2] = {{0.f,0.f,0.f,0.f},{0.f,0.f,0.f,0.f}};
    #pragma unroll
    for (int s = 0; s < 2; ++s)
      #pragma unroll
      for (int f = 0; f < 2; ++f) {
        s0[f] = __builtin_amdgcn_mfma_f32_16x16x32_bf16(bk[f][s], aq[0][s], s0[f], 0, 0, 0);
        s1[f] = __builtin_amdgcn_mfma_f32_16x16x32_bf16(bk[f][s], aq[1][s], s1[f], 0, 0, 0);
      }

    // ---- u0: normalize, store attn (nontemporal), PV ----
    f32x4 pv[2];
    #pragma unroll
    for (int f = 0; f < 2; ++f)
      #pragma unroll
      for (int r = 0; r < 4; ++r)
        pv[f][r] = EXP2(s0[f][r]) * rl0;

    float* arow = attnb + (size_t)l15 * LL + kt * 32 + lg * 4;
    __builtin_nontemporal_store(pv[0], (f32x4*)(arow));
    __builtin_nontemporal_store(pv[1], (f32x4*)(arow + 16));

    #pragma unroll
    for (int f = 0; f < 2; ++f) {
      bf16x4 pb;
      #pragma unroll
      for (int r = 0; r < 4; ++r) pb[r] = (__bf16)pv[f][r];
      *(bf16x4*)(prow + f * 16 + lg * 4) = pb;
    }
    bf16x8 pa = *(const bf16x8*)(prow + lg * 8);
    #pragma unroll
    for (int g = 0; g < 4; ++g)
      cacc0[g] = __builtin_amdgcn_mfma_f32_16x16x32_bf16(pa, bvc[g], cacc0[g], 0, 0, 0);

    // ---- u1: accumulate denominator ----
    #pragma unroll
    for (int f = 0; f < 2; ++f)
      #pragma unroll
      for (int r = 0; r < 4; ++r)
        ls1 += EXP2(s1[f][r]);
  }
  ls1 += __shfl_xor(ls1, 16, 64);
  ls1 += __shfl_xor(ls1, 32, 64);
  const float rl1 = 1.0f / ls1;

  // ================= phase C: pass2(u1) ====================================
  #pragma unroll
  for (int g = 0; g < 4; ++g)
    bvn[g] = *(const bf16x8*)(vb + (size_t)(g * 16 + l15) * LL + lg * 8);

  for (int kt = 0; kt < LL / 32; ++kt) {
    bf16x8 bvc[4];
    #pragma unroll
    for (int g = 0; g < 4; ++g) bvc[g] = bvn[g];
    if (kt + 1 < LL / 32) {
      #pragma unroll
      for (int g = 0; g < 4; ++g)
        bvn[g] = *(const bf16x8*)(vb + (size_t)(g * 16 + l15) * LL
                                     + (kt + 1) * 32 + lg * 8);
    }

    bf16x8 bk[2][2];
    #pragma unroll
    for (int f = 0; f < 2; ++f)
      #pragma unroll
      for (int s = 0; s < 2; ++s)
        bk[f][s] = *(const bf16x8*)(Klds + (kt * 32 + f * 16 + l15) * 64
                                         + ((s * 32 + lg * 8) ^ xsw));

    f32x4 s1[2] = {{0.f,0.f,0.f,0.f},{0.f,0.f,0.f,0.f}};
    #pragma unroll
    for (int s = 0; s < 2; ++s)
      #pragma unroll
      for (int f = 0; f < 2; ++f)
        s1[f] = __builtin_amdgcn_mfma_f32_16x16x32_bf16(bk[f][s], aq[1][s], s1[f], 0, 0, 0);

    f32x4 pv[2];
    #pragma unroll
    for (int f = 0; f < 2; ++f)
      #pragma unroll
      for (int r = 0; r < 4; ++r)
        pv[f][r] = EXP2(s1[f][r]) * rl1;

    float* arow = attnb + (size_t)(16 + l15) * LL + kt * 32 + lg * 4;
    __builtin_nontemporal_store(pv[0], (f32x4*)(arow));
    __builtin_nontemporal_store(pv[1], (f32x4*)(arow + 16));

    #pragma unroll
    for (int f = 0; f < 2; ++f) {
      bf16x4 pb;
      #pragma unroll
      for (int r = 0; r < 4; ++r) pb[r] = (__bf16)pv[f][r];
      *(bf16x4*)(prow + f * 16 + lg * 4) = pb;
    }
    bf16x8 pa = *(const bf16x8*)(prow + lg * 8);
    #pragma unroll
    for (int g = 0; g < 4; ++g)
      cacc1[g] = __builtin_amdgcn_mfma_f32_16x16x32_bf16(pa, bvc[g], cacc1[g], 0, 0, 0);
  }

  // ---- context epilogue (both subtiles) ----
  #pragma unroll
  for (int g = 0; g < 4; ++g)
    #pragma unroll
    for (int r = 0; r < 4; ++r) {
      ctxb[(size_t)(lg * 4 + r) * DD + g * 16 + l15]        = cacc0[g][r];
      ctxb[(size_t)(16 + lg * 4 + r) * DD + g * 16 + l15]   = cacc1[g][r];
    }
}

// ====================== fallback (R1 kernel, proven 151.7 µs) ===============
#define BQ 64
#define BK 32
#define KSTRIDE 72
#define VSTRIDE 40
#define PSTRIDE 48

__global__ __launch_bounds__(256, 4)
void sdpa_fallback(const float* __restrict__ q, const float* __restrict__ k,
                   const float* __restrict__ v, const float* __restrict__ scale_p,
                   float* __restrict__ out) {
  const int tid  = threadIdx.x;
  const int lane = tid & 63;
  const int w    = tid >> 6;
  int bid = blockIdx.x;
  bid = (bid & 7) * 128 + (bid >> 3);
  const int b    = bid >> 4;
  const int qblk = (bid & 15) * BQ;

  __shared__ __bf16 Ks[BK * KSTRIDE];
  __shared__ __bf16 Vs[DD * VSTRIDE];
  __shared__ __bf16 Pp[4][16 * PSTRIDE];

  const float scale = scale_p[0];
  const float* qb = q + ((size_t)b * LL + qblk) * DD;
  const float* kb = k + (size_t)b * LL * DD;
  const float* vb = v + (size_t)b * LL * DD;
  float* ctx  = out + ((size_t)b * LL + qblk) * DD;
  float* attn = out + (size_t)NB * LL * DD + (size_t)b * LL * LL + (size_t)qblk * LL;

  const int l15 = lane & 15;
  const int lg  = lane >> 4;
  const int dchunk = lg * 8;

  bf16x8 aq[2];
  {
    const float* qrow = qb + (size_t)(w * 16 + l15) * DD;
    #pragma unroll
    for (int s = 0; s < 2; ++s) {
      const f32x4* p4 = (const f32x4*)(qrow + s * 32 + dchunk);
      f32x4 x0 = p4[0], x1 = p4[1];
      #pragma unroll
      for (int j = 0; j < 4; ++j) {
        aq[s][j]     = (__bf16)(x0[j] * scale);
        aq[s][4 + j] = (__bf16)(x1[j] * scale);
      }
    }
  }

  const int srow = tid >> 3;
  const int sd0  = (tid & 7) * 8;

  float lpart[4] = {0.f, 0.f, 0.f, 0.f};
  for (int kt = 0; kt < LL / BK; ++kt) {
    __syncthreads();
    {
      const f32x4* src = (const f32x4*)(kb + (size_t)(kt * BK + srow) * DD + sd0);
      f32x4 x0 = src[0], x1 = src[1];
      bf16x8 t;
      #pragma unroll
      for (int j = 0; j < 4; ++j) { t[j] = (__bf16)x0[j]; t[4 + j] = (__bf16)x1[j]; }
      *(bf16x8*)&Ks[srow * KSTRIDE + sd0] = t;
    }
    __syncthreads();
    f32x4 sacc[2] = {{0.f,0.f,0.f,0.f},{0.f,0.f,0.f,0.f}};
    #pragma unroll
    for (int s = 0; s < 2; ++s)
      #pragma unroll
      for (int f = 0; f < 2; ++f) {
        bf16x8 bk = *(const bf16x8*)&Ks[(f * 16 + l15) * KSTRIDE + s * 32 + dchunk];
        sacc[f] = __builtin_amdgcn_mfma_f32_16x16x32_bf16(aq[s], bk, sacc[f], 0, 0, 0);
      }
    #pragma unroll
    for (int f = 0; f < 2; ++f)
      #pragma unroll
      for (int r = 0; r < 4; ++r)
        lpart[r] += __expf(sacc[f][r]);
  }
  #pragma unroll
  for (int m = 1; m < 16; m <<= 1)
    #pragma unroll
    for (int r = 0; r < 4; ++r)
      lpart[r] += __shfl_xor(lpart[r], m, 64);
  float rl[4];
  #pragma unroll
  for (int r = 0; r < 4; ++r) rl[r] = 1.0f / lpart[r];

  f32x4 cacc[4] = {{0.f,0.f,0.f,0.f},{0.f,0.f,0.f,0.f},
                   {0.f,0.f,0.f,0.f},{0.f,0.f,0.f,0.f}};
  for (int kt = 0; kt < LL / BK; ++kt) {
    __syncthreads();
    {
      const f32x4* src = (const f32x4*)(kb + (size_t)(kt * BK + srow) * DD + sd0);
      f32x4 x0 = src[0], x1 = src[1];
      bf16x8 t;
      #pragma unroll
      for (int j = 0; j < 4; ++j) { t[j] = (__bf16)x0[j]; t[4 + j] = (__bf16)x1[j]; }
      *(bf16x8*)&Ks[srow * KSTRIDE + sd0] = t;
      const f32x4* vsrc = (const f32x4*)(vb + (size_t)(kt * BK + srow) * DD + sd0);
      f32x4 y0 = vsrc[0], y1 = vsrc[1];
      #pragma unroll
      for (int j = 0; j < 4; ++j) {
        Vs[(sd0 + j)     * VSTRIDE + srow] = (__bf16)y0[j];
        Vs[(sd0 + 4 + j) * VSTRIDE + srow] = (__bf16)y1[j];
      }
    }
    __syncthreads();
    f32x4 sacc[2] = {{0.f,0.f,0.f,0.f},{0.f,0.f,0.f,0.f}};
    #pragma unroll
    for (int s = 0; s < 2; ++s)
      #pragma unroll
      for (int f = 0; f < 2; ++f) {
        bf16x8 bk = *(const bf16x8*)&Ks[(f * 16 + l15) * KSTRIDE + s * 32 + dchunk];
        sacc[f] = __builtin_amdgcn_mfma_f32_16x16x32_bf16(aq[s], bk, sacc[f], 0, 0, 0);
      }
    #pragma unroll
    for (int f = 0; f < 2; ++f)
      #pragma unroll
      for (int r = 0; r < 4; ++r) {
        const int row = lg * 4 + r;
        float p = __expf(sacc[f][r]) * rl[r];
        attn[(size_t)(w * 16 + row) * LL + (kt * BK + f * 16 + l15)] = p;
        Pp[w][row * PSTRIDE + f * 16 + l15] = (__bf16)p;
      }
    bf16x8 pa = *(const bf16x8*)&Pp[w][l15 * PSTRIDE + lg * 8];
    #pragma unroll
    for (int g = 0; g < 4; ++g) {
      bf16x8 bv = *(const bf16x8*)&Vs[(g * 16 + l15) * VSTRIDE + lg * 8];
      cacc[g] = __builtin_amdgcn_mfma_f32_16x16x32_bf16(pa, bv, cacc[g], 0, 0, 0);
    }
  }
  #pragma unroll
  for (int g = 0; g < 4; ++g)
    #pragma unroll
    for (int r = 0; r < 4; ++r)
      ctx[(size_t)(w * 16 + lg * 4 + r) * DD + g * 16 + l15] = cacc[g][r];
}

extern "C" void kernel_launch(void* const* d_in, const int* in_sizes, int n_in,
                              void* d_out, int out_size, void* d_ws, size_t ws_size,
                              hipStream_t stream) {
  const float* q = (const float*)d_in[0];
  const float* k = (const float*)d_in[1];
  const float* v = (const float*)d_in[2];
  const float* s = (const float*)d_in[3];
  float* out = (float*)d_out;

  const size_t vbytes = (size_t)NB * LL * DD * 2;   // 8 MB for V^T bf16
  if (ws_size >= vbytes) {
    __bf16* vt = (__bf16*)d_ws;
    preconvert_v<<<dim3(NB * (LL / 64)), dim3(256), 0, stream>>>(v, vt);
    (void)hipFuncSetAttribute((const void*)sdpa_fused,
                              hipFuncAttributeMaxDynamicSharedMemorySize,
                              LDS_TOTAL);
    sdpa_fused<<<dim3(256), dim3(512), LDS_TOTAL, stream>>>(q, k, vt, s, out);
  } else {
    sdpa_fallback<<<dim3(NB * (LL / 64)), dim3(256), 0, stream>>>(q, k, v, s, out);
  }
}

// Round 12
// 107.193 us; speedup vs baseline: 1.1637x; 1.1518x over previous
//
#include <hip/hip_runtime.h>
#include <hip/hip_bf16.h>

typedef __bf16 bf16x8 __attribute__((ext_vector_type(8)));
typedef __bf16 bf16x4 __attribute__((ext_vector_type(4)));
typedef float  f32x4  __attribute__((ext_vector_type(4)));

#define NB 64
#define LL 1024
#define DD 64
#define PB 40   // bf16 stride for Pw rows (80 B: b128-aligned, low-conflict)

#define LDS_K_BYTES (LL * DD * 2)                       // 128 KiB
#define LDS_TOTAL   (LDS_K_BYTES + 8 * 16 * PB * 2)     // +10 KiB Pw

#if __has_builtin(__builtin_amdgcn_exp2f)
#define EXP2(x) __builtin_amdgcn_exp2f(x)
#else
#define EXP2(x) exp2f(x)
#endif

// ---------------- V pre-pass: transpose+convert V -> Vt bf16 [b][d][key] ----
__global__ __launch_bounds__(256)
void preconvert_v(const float* __restrict__ v, __bf16* __restrict__ vt) {
  const int blk = blockIdx.x, tid = threadIdx.x;
  const int b = blk >> 4, t = blk & 15;   // 64-key tile t of batch b
  __shared__ float tile[64][65];
  const float* src = v + ((size_t)b * LL + t * 64) * DD;
  for (int i = tid; i < 64 * 16; i += 256) {
    const int row = i >> 4, c4 = (i & 15) * 4;
    f32x4 x = *(const f32x4*)(src + row * DD + c4);
    tile[row][c4 + 0] = x[0]; tile[row][c4 + 1] = x[1];
    tile[row][c4 + 2] = x[2]; tile[row][c4 + 3] = x[3];
  }
  __syncthreads();
  __bf16* dst = vt + (size_t)b * DD * LL + t * 64;
  for (int i = tid; i < 64 * 8; i += 256) {
    const int d = i >> 3, k8 = (i & 7) * 8;
    bf16x8 o;
    #pragma unroll
    for (int j = 0; j < 8; ++j) o[j] = (__bf16)tile[k8 + j][d];
    *(bf16x8*)(dst + (size_t)d * LL + k8) = o;
  }
}

// ---------------- fused main: whole-K-in-LDS, phase-interleaved waves -------
__global__ __launch_bounds__(512, 1)
void sdpa_fused(const float* __restrict__ q, const float* __restrict__ kf,
                const __bf16* __restrict__ vt, const float* __restrict__ scale_p,
                float* __restrict__ out) {
  extern __shared__ char smem[];
  __bf16* Klds = (__bf16*)smem;                     // [1024][64], XOR-swizzled
  __bf16* Pw   = (__bf16*)(smem + LDS_K_BYTES);     // [8 waves][16][PB]

  const int tid  = threadIdx.x;
  const int lane = tid & 63;
  const int w    = tid >> 6;
  const int l15  = lane & 15;
  const int lg   = lane >> 4;

  int bid = blockIdx.x;                      // 256 blocks
  bid = (bid & 7) * 32 + (bid >> 3);         // XCD j -> batches [j*8, j*8+8)
  const int b     = bid >> 2;
  const int qrow0 = (bid & 3) * 256 + w * 32;

  // fold log2(e) into the scale: v_exp_f32 computes 2^x natively
  const float scale2 = scale_p[0] * 1.4426950408889634f;
  const float* kb = kf + (size_t)b * LL * DD;       // fp32 K of this batch
  const __bf16* vb = vt + (size_t)b * DD * LL;      // bf16 V^T of this batch
  float* ctxb  = out + ((size_t)b * LL + qrow0) * DD;
  float* attnb = out + (size_t)NB * LL * DD + (size_t)b * LL * LL
               + (size_t)qrow0 * LL;

  // ---- stage ALL of K: fp32 global -> bf16 LDS, swizzled ----
  #pragma unroll
  for (int it = 0; it < 16; ++it) {
    const int c = it * 512 + tid;            // 8192 chunks of 8 elems
    const int row = c >> 3, slot = c & 7;
    const f32x4* s4 = (const f32x4*)(kb + (size_t)c * 8);
    f32x4 x0 = s4[0], x1 = s4[1];
    bf16x8 t;
    #pragma unroll
    for (int j = 0; j < 4; ++j) { t[j] = (__bf16)x0[j]; t[4 + j] = (__bf16)x1[j]; }
    *(bf16x8*)(Klds + row * 64 + ((slot * 8) ^ ((row & 7) * 8))) = t;
  }

  // ---- Q fragments, 2 subtiles of 16 rows (scale2 folded) ----
  bf16x8 aq[2][2];
  #pragma unroll
  for (int u = 0; u < 2; ++u) {
    const float* qrow = q + ((size_t)b * LL + qrow0 + u * 16 + l15) * DD;
    #pragma unroll
    for (int s = 0; s < 2; ++s) {
      const f32x4* p4 = (const f32x4*)(qrow + s * 32 + lg * 8);
      f32x4 x0 = p4[0], x1 = p4[1];
      #pragma unroll
      for (int j = 0; j < 4; ++j) {
        aq[u][s][j]     = (__bf16)(x0[j] * scale2);
        aq[u][s][4 + j] = (__bf16)(x1[j] * scale2);
      }
    }
  }

  __syncthreads();   // K resident — the only barrier

  const int xsw = (l15 & 7) * 8;            // read-side swizzle
  __bf16* prow = Pw + (w * 16 + l15) * PB;  // wave-private P row (q = l15)

  // ================= phase A: pass1(u0) — denominators only ================
  float ls0 = 0.f;
  for (int kt = 0; kt < LL / 32; ++kt) {
    bf16x8 bk[2][2];
    #pragma unroll
    for (int f = 0; f < 2; ++f)
      #pragma unroll
      for (int s = 0; s < 2; ++s)
        bk[f][s] = *(const bf16x8*)(Klds + (kt * 32 + f * 16 + l15) * 64
                                         + ((s * 32 + lg * 8) ^ xsw));
    f32x4 sacc[2] = {{0.f,0.f,0.f,0.f},{0.f,0.f,0.f,0.f}};
    #pragma unroll
    for (int s = 0; s < 2; ++s)
      #pragma unroll
      for (int f = 0; f < 2; ++f)
        sacc[f] = __builtin_amdgcn_mfma_f32_16x16x32_bf16(bk[f][s], aq[0][s], sacc[f], 0, 0, 0);
    #pragma unroll
    for (int f = 0; f < 2; ++f)
      #pragma unroll
      for (int r = 0; r < 4; ++r)
        ls0 += EXP2(sacc[f][r]);
  }
  ls0 += __shfl_xor(ls0, 16, 64);
  ls0 += __shfl_xor(ls0, 32, 64);
  const float rl0 = 1.0f / ls0;

  // ============ phase B: pass2(u0) interleaved with pass1(u1) ==============
  f32x4 cacc0[4], cacc1[4];
  #pragma unroll
  for (int g = 0; g < 4; ++g) {
    cacc0[g] = (f32x4){0.f, 0.f, 0.f, 0.f};
    cacc1[g] = (f32x4){0.f, 0.f, 0.f, 0.f};
  }
  float ls1 = 0.f;

  bf16x8 bvn[4];
  #pragma unroll
  for (int g = 0; g < 4; ++g)
    bvn[g] = *(const bf16x8*)(vb + (size_t)(g * 16 + l15) * LL + lg * 8);

  for (int kt = 0; kt < LL / 32; ++kt) {
    bf16x8 bvc[4];
    #pragma unroll
    for (int g = 0; g < 4; ++g) bvc[g] = bvn[g];
    if (kt + 1 < LL / 32) {
      #pragma unroll
      for (int g = 0; g < 4; ++g)
        bvn[g] = *(const bf16x8*)(vb + (size_t)(g * 16 + l15) * LL
                                     + (kt + 1) * 32 + lg * 8);
    }

    bf16x8 bk[2][2];
    #pragma unroll
    for (int f = 0; f < 2; ++f)
      #pragma unroll
      for (int s = 0; s < 2; ++s)
        bk[f][s] = *(const bf16x8*)(Klds + (kt * 32 + f * 16 + l15) * 64
                                         + ((s * 32 + lg * 8) ^ xsw));

    // QK for BOTH subtiles off the same bk fragments
    f32x4 s0[2] = {{0.f,0.f,0.f,0.f},{0.f,0.f,0.f,0.f}};
    f32x4 s1[2] = {{0.f,0.f,0.f,0.f},{0.f,0.f,0.f,0.f}};
    #pragma unroll
    for (int s = 0; s < 2; ++s)
      #pragma unroll
      for (int f = 0; f < 2; ++f) {
        s0[f] = __builtin_amdgcn_mfma_f32_16x16x32_bf16(bk[f][s], aq[0][s], s0[f], 0, 0, 0);
        s1[f] = __builtin_amdgcn_mfma_f32_16x16x32_bf16(bk[f][s], aq[1][s], s1[f], 0, 0, 0);
      }

    // ---- u0: normalize, store attn, PV ----
    f32x4 pv[2];
    #pragma unroll
    for (int f = 0; f < 2; ++f)
      #pragma unroll
      for (int r = 0; r < 4; ++r)
        pv[f][r] = EXP2(s0[f][r]) * rl0;

    float* arow = attnb + (size_t)l15 * LL + kt * 32 + lg * 4;
    *(f32x4*)(arow)      = pv[0];
    *(f32x4*)(arow + 16) = pv[1];

    #pragma unroll
    for (int f = 0; f < 2; ++f) {
      bf16x4 pb;
      #pragma unroll
      for (int r = 0; r < 4; ++r) pb[r] = (__bf16)pv[f][r];
      *(bf16x4*)(prow + f * 16 + lg * 4) = pb;
    }
    bf16x8 pa = *(const bf16x8*)(prow + lg * 8);
    #pragma unroll
    for (int g = 0; g < 4; ++g)
      cacc0[g] = __builtin_amdgcn_mfma_f32_16x16x32_bf16(pa, bvc[g], cacc0[g], 0, 0, 0);

    // ---- u1: accumulate denominator ----
    #pragma unroll
    for (int f = 0; f < 2; ++f)
      #pragma unroll
      for (int r = 0; r < 4; ++r)
        ls1 += EXP2(s1[f][r]);
  }
  ls1 += __shfl_xor(ls1, 16, 64);
  ls1 += __shfl_xor(ls1, 32, 64);
  const float rl1 = 1.0f / ls1;

  // ================= phase C: pass2(u1) ====================================
  #pragma unroll
  for (int g = 0; g < 4; ++g)
    bvn[g] = *(const bf16x8*)(vb + (size_t)(g * 16 + l15) * LL + lg * 8);

  for (int kt = 0; kt < LL / 32; ++kt) {
    bf16x8 bvc[4];
    #pragma unroll
    for (int g = 0; g < 4; ++g) bvc[g] = bvn[g];
    if (kt + 1 < LL / 32) {
      #pragma unroll
      for (int g = 0; g < 4; ++g)
        bvn[g] = *(const bf16x8*)(vb + (size_t)(g * 16 + l15) * LL
                                     + (kt + 1) * 32 + lg * 8);
    }

    bf16x8 bk[2][2];
    #pragma unroll
    for (int f = 0; f < 2; ++f)
      #pragma unroll
      for (int s = 0; s < 2; ++s)
        bk[f][s] = *(const bf16x8*)(Klds + (kt * 32 + f * 16 + l15) * 64
                                         + ((s * 32 + lg * 8) ^ xsw));

    f32x4 s1[2] = {{0.f,0.f,0.f,0.f},{0.f,0.f,0.f,0.f}};
    #pragma unroll
    for (int s = 0; s < 2; ++s)
      #pragma unroll
      for (int f = 0; f < 2; ++f)
        s1[f] = __builtin_amdgcn_mfma_f32_16x16x32_bf16(bk[f][s], aq[1][s], s1[f], 0, 0, 0);

    f32x4 pv[2];
    #pragma unroll
    for (int f = 0; f < 2; ++f)
      #pragma unroll
      for (int r = 0; r < 4; ++r)
        pv[f][r] = EXP2(s1[f][r]) * rl1;

    float* arow = attnb + (size_t)(16 + l15) * LL + kt * 32 + lg * 4;
    *(f32x4*)(arow)      = pv[0];
    *(f32x4*)(arow + 16) = pv[1];

    #pragma unroll
    for (int f = 0; f < 2; ++f) {
      bf16x4 pb;
      #pragma unroll
      for (int r = 0; r < 4; ++r) pb[r] = (__bf16)pv[f][r];
      *(bf16x4*)(prow + f * 16 + lg * 4) = pb;
    }
    bf16x8 pa = *(const bf16x8*)(prow + lg * 8);
    #pragma unroll
    for (int g = 0; g < 4; ++g)
      cacc1[g] = __builtin_amdgcn_mfma_f32_16x16x32_bf16(pa, bvc[g], cacc1[g], 0, 0, 0);
  }

  // ---- context epilogue (both subtiles) ----
  #pragma unroll
  for (int g = 0; g < 4; ++g)
    #pragma unroll
    for (int r = 0; r < 4; ++r) {
      ctxb[(size_t)(lg * 4 + r) * DD + g * 16 + l15]        = cacc0[g][r];
      ctxb[(size_t)(16 + lg * 4 + r) * DD + g * 16 + l15]   = cacc1[g][r];
    }
}

// ====================== fallback (R1 kernel, proven 151.7 µs) ===============
#define BQ 64
#define BK 32
#define KSTRIDE 72
#define VSTRIDE 40
#define PSTRIDE 48

__global__ __launch_bounds__(256, 4)
void sdpa_fallback(const float* __restrict__ q, const float* __restrict__ k,
                   const float* __restrict__ v, const float* __restrict__ scale_p,
                   float* __restrict__ out) {
  const int tid  = threadIdx.x;
  const int lane = tid & 63;
  const int w    = tid >> 6;
  int bid = blockIdx.x;
  bid = (bid & 7) * 128 + (bid >> 3);
  const int b    = bid >> 4;
  const int qblk = (bid & 15) * BQ;

  __shared__ __bf16 Ks[BK * KSTRIDE];
  __shared__ __bf16 Vs[DD * VSTRIDE];
  __shared__ __bf16 Pp[4][16 * PSTRIDE];

  const float scale = scale_p[0];
  const float* qb = q + ((size_t)b * LL + qblk) * DD;
  const float* kb = k + (size_t)b * LL * DD;
  const float* vb = v + (size_t)b * LL * DD;
  float* ctx  = out + ((size_t)b * LL + qblk) * DD;
  float* attn = out + (size_t)NB * LL * DD + (size_t)b * LL * LL + (size_t)qblk * LL;

  const int l15 = lane & 15;
  const int lg  = lane >> 4;
  const int dchunk = lg * 8;

  bf16x8 aq[2];
  {
    const float* qrow = qb + (size_t)(w * 16 + l15) * DD;
    #pragma unroll
    for (int s = 0; s < 2; ++s) {
      const f32x4* p4 = (const f32x4*)(qrow + s * 32 + dchunk);
      f32x4 x0 = p4[0], x1 = p4[1];
      #pragma unroll
      for (int j = 0; j < 4; ++j) {
        aq[s][j]     = (__bf16)(x0[j] * scale);
        aq[s][4 + j] = (__bf16)(x1[j] * scale);
      }
    }
  }

  const int srow = tid >> 3;
  const int sd0  = (tid & 7) * 8;

  float lpart[4] = {0.f, 0.f, 0.f, 0.f};
  for (int kt = 0; kt < LL / BK; ++kt) {
    __syncthreads();
    {
      const f32x4* src = (const f32x4*)(kb + (size_t)(kt * BK + srow) * DD + sd0);
      f32x4 x0 = src[0], x1 = src[1];
      bf16x8 t;
      #pragma unroll
      for (int j = 0; j < 4; ++j) { t[j] = (__bf16)x0[j]; t[4 + j] = (__bf16)x1[j]; }
      *(bf16x8*)&Ks[srow * KSTRIDE + sd0] = t;
    }
    __syncthreads();
    f32x4 sacc[2] = {{0.f,0.f,0.f,0.f},{0.f,0.f,0.f,0.f}};
    #pragma unroll
    for (int s = 0; s < 2; ++s)
      #pragma unroll
      for (int f = 0; f < 2; ++f) {
        bf16x8 bk = *(const bf16x8*)&Ks[(f * 16 + l15) * KSTRIDE + s * 32 + dchunk];
        sacc[f] = __builtin_amdgcn_mfma_f32_16x16x32_bf16(aq[s], bk, sacc[f], 0, 0, 0);
      }
    #pragma unroll
    for (int f = 0; f < 2; ++f)
      #pragma unroll
      for (int r = 0; r < 4; ++r)
        lpart[r] += __expf(sacc[f][r]);
  }
  #pragma unroll
  for (int m = 1; m < 16; m <<= 1)
    #pragma unroll
    for (int r = 0; r < 4; ++r)
      lpart[r] += __shfl_xor(lpart[r], m, 64);
  float rl[4];
  #pragma unroll
  for (int r = 0; r < 4; ++r) rl[r] = 1.0f / lpart[r];

  f32x4 cacc[4] = {{0.f,0.f,0.f,0.f},{0.f,0.f,0.f,0.f},
                   {0.f,0.f,0.f,0.f},{0.f,0.f,0.f,0.f}};
  for (int kt = 0; kt < LL / BK; ++kt) {
    __syncthreads();
    {
      const f32x4* src = (const f32x4*)(kb + (size_t)(kt * BK + srow) * DD + sd0);
      f32x4 x0 = src[0], x1 = src[1];
      bf16x8 t;
      #pragma unroll
      for (int j = 0; j < 4; ++j) { t[j] = (__bf16)x0[j]; t[4 + j] = (__bf16)x1[j]; }
      *(bf16x8*)&Ks[srow * KSTRIDE + sd0] = t;
      const f32x4* vsrc = (const f32x4*)(vb + (size_t)(kt * BK + srow) * DD + sd0);
      f32x4 y0 = vsrc[0], y1 = vsrc[1];
      #pragma unroll
      for (int j = 0; j < 4; ++j) {
        Vs[(sd0 + j)     * VSTRIDE + srow] = (__bf16)y0[j];
        Vs[(sd0 + 4 + j) * VSTRIDE + srow] = (__bf16)y1[j];
      }
    }
    __syncthreads();
    f32x4 sacc[2] = {{0.f,0.f,0.f,0.f},{0.f,0.f,0.f,0.f}};
    #pragma unroll
    for (int s = 0; s < 2; ++s)
      #pragma unroll
      for (int f = 0; f < 2; ++f) {
        bf16x8 bk = *(const bf16x8*)&Ks[(f * 16 + l15) * KSTRIDE + s * 32 + dchunk];
        sacc[f] = __builtin_amdgcn_mfma_f32_16x16x32_bf16(aq[s], bk, sacc[f], 0, 0, 0);
      }
    #pragma unroll
    for (int f = 0; f < 2; ++f)
      #pragma unroll
      for (int r = 0; r < 4; ++r) {
        const int row = lg * 4 + r;
        float p = __expf(sacc[f][r]) * rl[r];
        attn[(size_t)(w * 16 + row) * LL + (kt * BK + f * 16 + l15)] = p;
        Pp[w][row * PSTRIDE + f * 16 + l15] = (__bf16)p;
      }
    bf16x8 pa = *(const bf16x8*)&Pp[w][l15 * PSTRIDE + lg * 8];
    #pragma unroll
    for (int g = 0; g < 4; ++g) {
      bf16x8 bv = *(const bf16x8*)&Vs[(g * 16 + l15) * VSTRIDE + lg * 8];
      cacc[g] = __builtin_amdgcn_mfma_f32_16x16x32_bf16(pa, bv, cacc[g], 0, 0, 0);
    }
  }
  #pragma unroll
  for (int g = 0; g < 4; ++g)
    #pragma unroll
    for (int r = 0; r < 4; ++r)
      ctx[(size_t)(w * 16 + lg * 4 + r) * DD + g * 16 + l15] = cacc[g][r];
}

extern "C" void kernel_launch(void* const* d_in, const int* in_sizes, int n_in,
                              void* d_out, int out_size, void* d_ws, size_t ws_size,
                              hipStream_t stream) {
  const float* q = (const float*)d_in[0];
  const float* k = (const float*)d_in[1];
  const float* v = (const float*)d_in[2];
  const float* s = (const float*)d_in[3];
  float* out = (float*)d_out;

  const size_t vbytes = (size_t)NB * LL * DD * 2;   // 8 MB for V^T bf16
  if (ws_size >= vbytes) {
    __bf16* vt = (__bf16*)d_ws;
    preconvert_v<<<dim3(NB * (LL / 64)), dim3(256), 0, stream>>>(v, vt);
    (void)hipFuncSetAttribute((const void*)sdpa_fused,
                              hipFuncAttributeMaxDynamicSharedMemorySize,
                              LDS_TOTAL);
    sdpa_fused<<<dim3(256), dim3(512), LDS_TOTAL, stream>>>(q, k, vt, s, out);
  } else {
    sdpa_fallback<<<dim3(NB * (LL / 64)), dim3(256), 0, stream>>>(q, k, v, s, out);
  }
}